// Round 1
// baseline (190.876 us; speedup 1.0000x reference)
//
#include <hip/hip_runtime.h>

// MSDeformAttn: B=4, Lq=Lv=5440 (M=21760), C=256, heads=8, levels=4, points=4, hd=32
// Level shapes: (64,64),(32,32),(16,16),(8,8) -> starts 0,4096,5120,5376
//
// R10: barrier-free gemm12_cvt.
//  - R9 counters: gemm12_cvt 42.7us, MfmaUtil 5.8%, HBM 26%, 2.18M LDS bank
//    conflicts -> classic 2-phase stage+barrier critical path (m233: ~72%).
//  - B is a weight panel (128n x 256k = 64KB f16): stage ONCE into LDS in
//    MFMA-fragment-major order [(kt*4+g)][n][8] -> staging writes and K-loop
//    ds_read_b128 are consecutive-lane stride-1 (conflict-free).
//  - A fragments read DIRECT from global (wave = 16 rows x 128B contiguous),
//    1-deep software pipeline (issue kt+1 loads before kt's MFMA). Zero
//    barriers in the K-loop.
//  - Predict: gemm12 42.7 -> ~20us, MfmaUtil ~12-15%, conflicts ~0.
//  - sample_f16 and gemm_single byte-identical to R9.

typedef __attribute__((ext_vector_type(8))) _Float16 half8;
typedef __attribute__((ext_vector_type(4))) float f32x4;

typedef __attribute__((address_space(3))) unsigned int lds_uint;
typedef const __attribute__((address_space(1))) unsigned int g_uint;

__device__ __forceinline__ void load_lds16(const _Float16* g, _Float16* l) {
    __builtin_amdgcn_global_load_lds((g_uint*)g, (lds_uint*)l, 16, 0, 0);
}

__device__ __forceinline__ half8 splat8(_Float16 v) {
    half8 r = {v, v, v, v, v, v, v, v};
    return r;
}

#define M_TOTAL 21760

// -------- fused GEMM1+GEMM2 from f32 sources, 128x128 tiles ------------------
// B panel staged once (fragment-major), K-loop barrier-free with direct-global
// A fragment loads.
__global__ __launch_bounds__(256) void gemm12_cvt(
    const float* __restrict__ value, const float* __restrict__ query,
    const float* __restrict__ W_val, const float* __restrict__ W_off,
    const float* __restrict__ W_attn,
    const float* __restrict__ b_val, const float* __restrict__ b_off,
    const float* __restrict__ b_attn,
    _Float16* __restrict__ valh, _Float16* __restrict__ offh)
{
    // fragment-major B panel: slot = (kt*4 + g)*128 + n, 8 f16 per slot = 64KB
    __shared__ _Float16 Bs[32 * 128 * 8];

    const bool g1 = blockIdx.x < 340;
    const int id = g1 ? blockIdx.x : blockIdx.x - 340;
    const int mt = g1 ? (id >> 1) : (id / 3);
    const int nt = g1 ? (id & 1) : (id % 3);
    const int NN = g1 ? 256 : 384;
    const float* A = g1 ? value : query;
    _Float16* C = g1 ? valh : offh;
    const int bm = mt * 128;
    const int bn = nt * 128;

    const float* W;
    int sW, nb;
    if (g1)            { W = W_val;  sW = 256; nb = bn; }
    else if (nt < 2)   { W = W_off;  sW = 256; nb = bn; }
    else               { W = W_attn; sW = 128; nb = 0;  }

    const int tid = threadIdx.x;
    const int wave = tid >> 6, lane = tid & 63;
    const int wm = (wave & 1) * 64, wn = (wave >> 1) * 64;
    const int ml = lane & 15, kq = (lane >> 4) * 8;   // kq: f16/f32 k-offset in tile

    // ---- stage B panel once: thread owns column n_l, half the k range ----
    {
        const int n_l = tid & 127;
        const int kh = tid >> 7;                       // 0/1
#pragma unroll
        for (int ko = 0; ko < 128; ko += 8) {
            const int k = kh * 128 + ko;
            half8 h;
#pragma unroll
            for (int e = 0; e < 8; ++e)
                h[e] = (_Float16)W[(size_t)(k + e) * sW + nb + n_l];
            const int kt = k >> 5, g = (k >> 3) & 3;
            *(half8*)(Bs + ((kt * 4 + g) * 128 + n_l) * 8) = h;
        }
    }
    __syncthreads();   // the ONLY barrier

    const f32x4 zero4 = {0.f, 0.f, 0.f, 0.f};
    f32x4 acc[4][4];
#pragma unroll
    for (int i = 0; i < 4; ++i)
#pragma unroll
        for (int j = 0; j < 4; ++j) acc[i][j] = zero4;

    // per-lane base pointers
    const float* ap = A + (size_t)(bm + wm + ml) * 256 + kq;          // A row slice
    const _Float16* bsp = Bs + ((size_t)(lane >> 4) * 128 + wn + ml) * 8;

    // 1-deep software pipeline on A fragment loads
    float4 pa[4][2];
#pragma unroll
    for (int i = 0; i < 4; ++i) {
        const float* p = ap + (size_t)i * 16 * 256;
        pa[i][0] = *(const float4*)(p);
        pa[i][1] = *(const float4*)(p + 4);
    }

    for (int kt = 0; kt < 8; ++kt) {
        // convert current A fragments
        half8 af[4];
#pragma unroll
        for (int i = 0; i < 4; ++i) {
            const float4 a0 = pa[i][0];
            const float4 a1 = pa[i][1];
            af[i] = (half8){(_Float16)a0.x, (_Float16)a0.y, (_Float16)a0.z, (_Float16)a0.w,
                            (_Float16)a1.x, (_Float16)a1.y, (_Float16)a1.z, (_Float16)a1.w};
        }
        // issue next tile's A loads before the MFMA cluster
        if (kt < 7) {
#pragma unroll
            for (int i = 0; i < 4; ++i) {
                const float* p = ap + (size_t)i * 16 * 256 + (kt + 1) * 32;
                pa[i][0] = *(const float4*)(p);
                pa[i][1] = *(const float4*)(p + 4);
            }
        }
        // B fragments: consecutive-lane stride-1 ds_read_b128 (conflict-free)
        half8 bf[4];
#pragma unroll
        for (int j = 0; j < 4; ++j)
            bf[j] = *(const half8*)(bsp + ((size_t)kt * 4 * 128 + j * 16) * 8);
#pragma unroll
        for (int i = 0; i < 4; ++i)
#pragma unroll
            for (int j = 0; j < 4; ++j)
                acc[i][j] = __builtin_amdgcn_mfma_f32_16x16x32_f16(af[i], bf[j], acc[i][j], 0, 0, 0);
    }

    const int r0 = (lane >> 4) * 4;
#pragma unroll
    for (int j = 0; j < 4; ++j) {
        const int col = bn + wn + j * 16 + ml;
        const float bj = g1 ? b_val[col] : (col < 256 ? b_off[col] : b_attn[col - 256]);
#pragma unroll
        for (int i = 0; i < 4; ++i) {
            const size_t rbase = (size_t)(bm + wm + i * 16 + r0) * NN + col;
#pragma unroll
            for (int r = 0; r < 4; ++r)
                C[rbase + (size_t)r * NN] = (_Float16)(acc[i][j][r] + bj);
        }
    }
}

// -------- R4 GEMM core (DMA staging, pitch 32) for the final GEMM -------------
__device__ __forceinline__ void gemm_core(
    const _Float16* __restrict__ A, const _Float16* __restrict__ Bt,
    const float* __restrict__ bias, float* __restrict__ Cv,
    int NN, int mt, int nt)
{
    __shared__ _Float16 Ah[128 * 32];
    __shared__ _Float16 Bh[64 * 32];

    const int tid = threadIdx.x;
    const int bm = mt * 128;
    const int bn = nt * 64;
    const int wave = tid >> 6, lane = tid & 63;
    const int wm = (wave & 1) * 64, wn = (wave >> 1) * 32;
    const int ml = lane & 15, kq = (lane >> 4) * 8;
    const int lr = lane >> 2;
    const int lk = (lane & 3) * 8;

    const f32x4 zero4 = {0.f, 0.f, 0.f, 0.f};
    f32x4 acc[4][2];
#pragma unroll
    for (int i = 0; i < 4; ++i)
#pragma unroll
        for (int j = 0; j < 2; ++j) acc[i][j] = zero4;

    for (int kt = 0; kt < 8; ++kt) {
        const int k0 = kt * 32;
        __syncthreads();
#pragma unroll
        for (int t = 0; t < 2; ++t) {
            const int row = wave * 32 + t * 16;
            load_lds16(A + (size_t)(bm + row + lr) * 256 + k0 + lk,
                       Ah + (size_t)row * 32);
        }
        {
            const int row = wave * 16;
            load_lds16(Bt + (size_t)(bn + row + lr) * 256 + k0 + lk,
                       Bh + (size_t)row * 32);
        }
        __syncthreads();

        half8 af[4], bf[2];
#pragma unroll
        for (int i = 0; i < 4; ++i)
            af[i] = *(const half8*)(Ah + (wm + i * 16 + ml) * 32 + kq);
#pragma unroll
        for (int j = 0; j < 2; ++j)
            bf[j] = *(const half8*)(Bh + (wn + j * 16 + ml) * 32 + kq);
#pragma unroll
        for (int i = 0; i < 4; ++i)
#pragma unroll
            for (int j = 0; j < 2; ++j)
                acc[i][j] = __builtin_amdgcn_mfma_f32_16x16x32_f16(af[i], bf[j], acc[i][j], 0, 0, 0);
    }

    const int r0 = (lane >> 4) * 4;
#pragma unroll
    for (int j = 0; j < 2; ++j) {
        const int col = bn + wn + j * 16 + ml;
        const float bj = bias[col];
#pragma unroll
        for (int i = 0; i < 4; ++i) {
            const size_t rbase = (size_t)(bm + wm + i * 16 + r0) * NN + col;
#pragma unroll
            for (int r = 0; r < 4; ++r)
                Cv[rbase + (size_t)r * NN] = acc[i][j][r] + bj;
        }
    }
}

__global__ __launch_bounds__(256) void gemm_single(
    const _Float16* __restrict__ A, const _Float16* __restrict__ Bt,
    const float* __restrict__ bias, float* __restrict__ Cv)
{
    const int id = blockIdx.x;
    gemm_core(A, Bt, bias, Cv, 256, id >> 2, id & 3);
}

// ---------------- sampler: batched gathers, schedule pinned -------------------
__global__ __launch_bounds__(256, 4) void sample_f16(
    const _Float16* __restrict__ valh,   // [M,256] f16
    const float* __restrict__ refp,      // [B,Lq,4,2]
    const _Float16* __restrict__ offh,   // [M,384] f16: 0-255 offsets, 256-383 logits
    const float* __restrict__ W_out,     // [256,256] f32 (k-major)
    _Float16* __restrict__ wto,          // [256,256] f16 (n-major, k-contig)
    _Float16* __restrict__ acc_out)      // [M,256] f16
{
    // fold W_out transpose into the first 256 blocks (consumed next dispatch)
    if (blockIdx.x < 256)
        wto[blockIdx.x * 256 + threadIdx.x] =
            (_Float16)W_out[threadIdx.x * 256 + blockIdx.x];

    const int wave = threadIdx.x >> 6, lane = threadIdx.x & 63;
    const int q2 = lane >> 5, sl = lane & 31;
    const int bq = blockIdx.x * 8 + wave * 2 + q2;    // 0..21759
    const int b = bq / 5440;
    const int h = sl >> 2;          // head
    const int d8 = (sl & 3) * 8;    // channel octet within head

    const _Float16* off_row = offh + (size_t)bq * 384 + h * 32;
    const _Float16* att_row = offh + (size_t)bq * 384 + 256 + h * 16;
    const float* rp = refp + (size_t)bq * 8;

    const half8 ofr0 = *(const half8*)(off_row);
    const half8 ofr1 = *(const half8*)(off_row + 8);
    const half8 ofr2 = *(const half8*)(off_row + 16);
    const half8 ofr3 = *(const half8*)(off_row + 24);
    float lg[16];
    {
        const half8 t0 = *(const half8*)(att_row);
        const half8 t1 = *(const half8*)(att_row + 8);
#pragma unroll
        for (int j = 0; j < 8; ++j) { lg[j] = (float)t0[j]; lg[8 + j] = (float)t1[j]; }
    }
    float mx = -1e30f;
#pragma unroll
    for (int i = 0; i < 16; ++i) mx = fmaxf(mx, lg[i]);
    float s = 0.f;
#pragma unroll
    for (int i = 0; i < 16; ++i) { lg[i] = __expf(lg[i] - mx); s += lg[i]; }
    const float inv = 1.f / s;

    const float4 rp01 = *(const float4*)rp;
    const float4 rp23 = *(const float4*)(rp + 4);
    const float rxs[4] = {rp01.x, rp01.z, rp23.x, rp23.z};
    const float rys[4] = {rp01.y, rp01.w, rp23.y, rp23.w};

    const int Ws_[4] = {64, 32, 16, 8};
    const int starts_[4] = {0, 4096, 5120, 5376};

    half8 acc = splat8((_Float16)0.f);
#pragma unroll
    for (int l = 0; l < 4; ++l) {
        const int W = Ws_[l];
        const float fW = (float)W;
        const _Float16* vbase = valh + ((size_t)(b * 5440 + starts_[l])) * 256 + h * 32 + d8;
        const float rx = rxs[l], ry = rys[l];

        int idx_[16];
        _Float16 w_[16];
#pragma unroll
        for (int p = 0; p < 4; ++p) {
            const int pi = l * 4 + p;
            const float aw = lg[pi] * inv;
            float ox, oy;
            {
                const half8 src = (pi < 8) ? ((pi < 4) ? ofr0 : ofr1)
                                           : ((pi < 12) ? ofr2 : ofr3);
                const int e = (pi & 3) * 2;
                ox = (float)src[e];
                oy = (float)src[e + 1];
            }
            const float x = fmaf(rx, fW, ox) - 0.5f;
            const float y = fmaf(ry, fW, oy) - 0.5f;
            const float x0f = floorf(x), y0f = floorf(y);
            const int x0 = (int)x0f, y0 = (int)y0f;
            const float wx = x - x0f, wy = y - y0f;
            const bool okx0 = ((unsigned)x0 < (unsigned)W);
            const bool okx1 = ((unsigned)(x0 + 1) < (unsigned)W);
            const bool oky0 = ((unsigned)y0 < (unsigned)W);
            const bool oky1 = ((unsigned)(y0 + 1) < (unsigned)W);
            const int xc0 = min(max(x0, 0), W - 1);
            const int xc1 = min(max(x0 + 1, 0), W - 1);
            const int yc0 = min(max(y0, 0), W - 1);
            const int yc1 = min(max(y0 + 1, 0), W - 1);
            w_[p * 4 + 0] = (_Float16)((okx0 & oky0) ? (1.f - wx) * (1.f - wy) * aw : 0.f);
            w_[p * 4 + 1] = (_Float16)((okx1 & oky0) ? wx * (1.f - wy) * aw : 0.f);
            w_[p * 4 + 2] = (_Float16)((okx0 & oky1) ? (1.f - wx) * wy * aw : 0.f);
            w_[p * 4 + 3] = (_Float16)((okx1 & oky1) ? wx * wy * aw : 0.f);
            idx_[p * 4 + 0] = (yc0 * W + xc0) * 256;
            idx_[p * 4 + 1] = (yc0 * W + xc1) * 256;
            idx_[p * 4 + 2] = (yc1 * W + xc0) * 256;
            idx_[p * 4 + 3] = (yc1 * W + xc1) * 256;
        }

        // pin: all 16 loads issue before any consumer (progressive vmcnt drain)
        __builtin_amdgcn_sched_barrier(0);
        half8 c_[16];
#pragma unroll
        for (int i = 0; i < 16; ++i)
            c_[i] = *(const half8*)(vbase + idx_[i]);
        __builtin_amdgcn_sched_barrier(0);
#pragma unroll
        for (int i = 0; i < 16; ++i)
            acc += c_[i] * splat8(w_[i]);
    }

    *(half8*)(acc_out + (size_t)bq * 256 + h * 32 + d8) = acc;
}

extern "C" void kernel_launch(void* const* d_in, const int* in_sizes, int n_in,
                              void* d_out, int out_size, void* d_ws, size_t ws_size,
                              hipStream_t stream) {
    const float* query  = (const float*)d_in[0];
    const float* refp   = (const float*)d_in[1];
    const float* value  = (const float*)d_in[2];
    const float* W_off  = (const float*)d_in[3];
    const float* b_off  = (const float*)d_in[4];
    const float* W_attn = (const float*)d_in[5];
    const float* b_attn = (const float*)d_in[6];
    const float* W_val  = (const float*)d_in[7];
    const float* b_val  = (const float*)d_in[8];
    const float* W_out  = (const float*)d_in[9];
    const float* b_out  = (const float*)d_in[10];
    float* out = (float*)d_out;

    const size_t M = M_TOTAL;

    _Float16* valh  = (_Float16*)d_ws;                // M*256
    _Float16* offh  = valh + M * 256;                 // M*384
    _Float16* acc16 = offh + M * 384;                 // M*256
    _Float16* wto   = acc16 + M * 256;                // 256*256

    dim3 blk(256);
    gemm12_cvt<<<dim3(850), blk, 0, stream>>>(
        value, query, W_val, W_off, W_attn, b_val, b_off, b_attn, valh, offh);
    sample_f16<<<dim3(M / 8), blk, 0, stream>>>(valh, refp, offh, W_out, wto, acc16);
    gemm_single<<<dim3(680), blk, 0, stream>>>(acc16, wto, b_out, out);
}

// Round 2
// 172.475 us; speedup vs baseline: 1.1067x; 1.1067x over previous
//
#include <hip/hip_runtime.h>

// MSDeformAttn: B=4, Lq=Lv=5440 (M=21760), C=256, heads=8, levels=4, points=4, hd=32
// Level shapes: (64,64),(32,32),(16,16),(8,8) -> starts 0,4096,5120,5376
//
// R11: gemm12_cvt = R9 LDS pipeline + R10 frag-major layout + m248 2-phase dbuf.
//  - R10 post-mortem: barrier-free direct-global K-loop was LATENCY-bound
//    (2 blocks/CU, 1-deep pipeline vs ~300cy L2/L3) -> 52us, MfmaUtil 4.5%.
//    But frag-major LDS layout was conflict-free (2.18M -> 0, counter-verified).
//  - R11: double-buffered frag-major tiles [g][row][8] (A and B, 32KB total),
//    reg-staged f32->f16 cvt, ONE barrier per kt (dbuf makes it sufficient),
//    next-tile global loads issued before the barrier (latency hides under
//    barrier + ds_read + 16 MFMA).
//  - Predict: gemm12 -> 22-28us, MfmaUtil ~10%, conflicts ~0, total ~155.
//  - sample_f16 and gemm_single byte-identical to R9.

typedef __attribute__((ext_vector_type(8))) _Float16 half8;
typedef __attribute__((ext_vector_type(4))) float f32x4;

typedef __attribute__((address_space(3))) unsigned int lds_uint;
typedef const __attribute__((address_space(1))) unsigned int g_uint;

__device__ __forceinline__ void load_lds16(const _Float16* g, _Float16* l) {
    __builtin_amdgcn_global_load_lds((g_uint*)g, (lds_uint*)l, 16, 0, 0);
}

__device__ __forceinline__ half8 splat8(_Float16 v) {
    half8 r = {v, v, v, v, v, v, v, v};
    return r;
}

#define M_TOTAL 21760

// -------- fused GEMM1+GEMM2 from f32 sources, 128x128 tiles, BK=32 ------------
// Fragment-major dbuf LDS: tile buffer = [g=k/8][row][8 f16], 8KB per operand.
// One __syncthreads per K-tile; next tile's global loads in flight across it.
__global__ __launch_bounds__(256) void gemm12_cvt(
    const float* __restrict__ value, const float* __restrict__ query,
    const float* __restrict__ W_val, const float* __restrict__ W_off,
    const float* __restrict__ W_attn,
    const float* __restrict__ b_val, const float* __restrict__ b_off,
    const float* __restrict__ b_attn,
    _Float16* __restrict__ valh, _Float16* __restrict__ offh)
{
    __shared__ _Float16 Af[2][4 * 128 * 8];   // 8KB per buf
    __shared__ _Float16 Bf[2][4 * 128 * 8];

    const bool g1 = blockIdx.x < 340;
    const int id = g1 ? blockIdx.x : blockIdx.x - 340;
    const int mt = g1 ? (id >> 1) : (id / 3);
    const int nt = g1 ? (id & 1) : (id % 3);
    const int NN = g1 ? 256 : 384;
    const float* A = g1 ? value : query;
    _Float16* C = g1 ? valh : offh;
    const int bm = mt * 128;
    const int bn = nt * 128;

    const float* W;
    int sW, nb;
    if (g1)            { W = W_val;  sW = 256; nb = bn; }
    else if (nt < 2)   { W = W_off;  sW = 256; nb = bn; }
    else               { W = W_attn; sW = 128; nb = 0;  }

    const int tid = threadIdx.x;
    const int wave = tid >> 6, lane = tid & 63;
    const int wm = (wave & 1) * 64, wn = (wave >> 1) * 64;
    const int ml = lane & 15;
    const int gq = lane >> 4;          // fragment k-octet 0..3

    // staging roles: thread owns row/col sr, k-octet-pair sg
    const int sr = tid & 127;
    const int sg = tid >> 7;           // 0/1

    const float* aS = A + (size_t)(bm + sr) * 256 + sg * 16;
    const float* wS = W + (size_t)(sg * 16) * sW + nb + sr;

    float4 pa0, pa1, pa2, pa3;         // 16 f32 of A (row sr, k sg*16..+15)
    float pb[16];                      // 16 f32 of B (col sr, k sg*16..+15)

    auto LOAD = [&](int kt) {
        const float* p = aS + kt * 32;
        pa0 = *(const float4*)(p + 0);
        pa1 = *(const float4*)(p + 4);
        pa2 = *(const float4*)(p + 8);
        pa3 = *(const float4*)(p + 12);
        const float* q = wS + (size_t)kt * 32 * sW;
#pragma unroll
        for (int e = 0; e < 16; ++e) pb[e] = q[(size_t)e * sW];
    };

    auto WRITE = [&](int buf) {
        const half8 ha0 = {(_Float16)pa0.x, (_Float16)pa0.y, (_Float16)pa0.z, (_Float16)pa0.w,
                           (_Float16)pa1.x, (_Float16)pa1.y, (_Float16)pa1.z, (_Float16)pa1.w};
        const half8 ha1 = {(_Float16)pa2.x, (_Float16)pa2.y, (_Float16)pa2.z, (_Float16)pa2.w,
                           (_Float16)pa3.x, (_Float16)pa3.y, (_Float16)pa3.z, (_Float16)pa3.w};
        const half8 hb0 = {(_Float16)pb[0], (_Float16)pb[1], (_Float16)pb[2], (_Float16)pb[3],
                           (_Float16)pb[4], (_Float16)pb[5], (_Float16)pb[6], (_Float16)pb[7]};
        const half8 hb1 = {(_Float16)pb[8], (_Float16)pb[9], (_Float16)pb[10], (_Float16)pb[11],
                           (_Float16)pb[12], (_Float16)pb[13], (_Float16)pb[14], (_Float16)pb[15]};
        _Float16* ab = &Af[buf][0];
        _Float16* bb = &Bf[buf][0];
        *(half8*)(ab + (((sg * 2) * 128 + sr) << 3)) = ha0;
        *(half8*)(ab + (((sg * 2 + 1) * 128 + sr) << 3)) = ha1;
        *(half8*)(bb + (((sg * 2) * 128 + sr) << 3)) = hb0;
        *(half8*)(bb + (((sg * 2 + 1) * 128 + sr) << 3)) = hb1;
    };

    const f32x4 zero4 = {0.f, 0.f, 0.f, 0.f};
    f32x4 acc[4][4];
#pragma unroll
    for (int i = 0; i < 4; ++i)
#pragma unroll
        for (int j = 0; j < 4; ++j) acc[i][j] = zero4;

    LOAD(0);
    int cur = 0;
    for (int kt = 0; kt < 8; ++kt) {
        WRITE(cur);                      // cvt + conflict-free ds_write_b128
        if (kt < 7) LOAD(kt + 1);        // next tile's loads in flight across barrier
        __syncthreads();                 // the only barrier per K-tile

        half8 af[4], bf[4];
        const _Float16* ab = &Af[cur][0] + ((size_t)gq * 128 << 3);
        const _Float16* bb = &Bf[cur][0] + ((size_t)gq * 128 << 3);
#pragma unroll
        for (int i = 0; i < 4; ++i)
            af[i] = *(const half8*)(ab + ((wm + i * 16 + ml) << 3));
#pragma unroll
        for (int j = 0; j < 4; ++j)
            bf[j] = *(const half8*)(bb + ((wn + j * 16 + ml) << 3));
#pragma unroll
        for (int i = 0; i < 4; ++i)
#pragma unroll
            for (int j = 0; j < 4; ++j)
                acc[i][j] = __builtin_amdgcn_mfma_f32_16x16x32_f16(af[i], bf[j], acc[i][j], 0, 0, 0);
        cur ^= 1;
    }

    const int r0 = (lane >> 4) * 4;
#pragma unroll
    for (int j = 0; j < 4; ++j) {
        const int col = bn + wn + j * 16 + ml;
        const float bj = g1 ? b_val[col] : (col < 256 ? b_off[col] : b_attn[col - 256]);
#pragma unroll
        for (int i = 0; i < 4; ++i) {
            const size_t rbase = (size_t)(bm + wm + i * 16 + r0) * NN + col;
#pragma unroll
            for (int r = 0; r < 4; ++r)
                C[rbase + (size_t)r * NN] = (_Float16)(acc[i][j][r] + bj);
        }
    }
}

// -------- R4 GEMM core (DMA staging, pitch 32) for the final GEMM -------------
__device__ __forceinline__ void gemm_core(
    const _Float16* __restrict__ A, const _Float16* __restrict__ Bt,
    const float* __restrict__ bias, float* __restrict__ Cv,
    int NN, int mt, int nt)
{
    __shared__ _Float16 Ah[128 * 32];
    __shared__ _Float16 Bh[64 * 32];

    const int tid = threadIdx.x;
    const int bm = mt * 128;
    const int bn = nt * 64;
    const int wave = tid >> 6, lane = tid & 63;
    const int wm = (wave & 1) * 64, wn = (wave >> 1) * 32;
    const int ml = lane & 15, kq = (lane >> 4) * 8;
    const int lr = lane >> 2;
    const int lk = (lane & 3) * 8;

    const f32x4 zero4 = {0.f, 0.f, 0.f, 0.f};
    f32x4 acc[4][2];
#pragma unroll
    for (int i = 0; i < 4; ++i)
#pragma unroll
        for (int j = 0; j < 2; ++j) acc[i][j] = zero4;

    for (int kt = 0; kt < 8; ++kt) {
        const int k0 = kt * 32;
        __syncthreads();
#pragma unroll
        for (int t = 0; t < 2; ++t) {
            const int row = wave * 32 + t * 16;
            load_lds16(A + (size_t)(bm + row + lr) * 256 + k0 + lk,
                       Ah + (size_t)row * 32);
        }
        {
            const int row = wave * 16;
            load_lds16(Bt + (size_t)(bn + row + lr) * 256 + k0 + lk,
                       Bh + (size_t)row * 32);
        }
        __syncthreads();

        half8 af[4], bf[2];
#pragma unroll
        for (int i = 0; i < 4; ++i)
            af[i] = *(const half8*)(Ah + (wm + i * 16 + ml) * 32 + kq);
#pragma unroll
        for (int j = 0; j < 2; ++j)
            bf[j] = *(const half8*)(Bh + (wn + j * 16 + ml) * 32 + kq);
#pragma unroll
        for (int i = 0; i < 4; ++i)
#pragma unroll
            for (int j = 0; j < 2; ++j)
                acc[i][j] = __builtin_amdgcn_mfma_f32_16x16x32_f16(af[i], bf[j], acc[i][j], 0, 0, 0);
    }

    const int r0 = (lane >> 4) * 4;
#pragma unroll
    for (int j = 0; j < 2; ++j) {
        const int col = bn + wn + j * 16 + ml;
        const float bj = bias[col];
#pragma unroll
        for (int i = 0; i < 4; ++i) {
            const size_t rbase = (size_t)(bm + wm + i * 16 + r0) * NN + col;
#pragma unroll
            for (int r = 0; r < 4; ++r)
                Cv[rbase + (size_t)r * NN] = acc[i][j][r] + bj;
        }
    }
}

__global__ __launch_bounds__(256) void gemm_single(
    const _Float16* __restrict__ A, const _Float16* __restrict__ Bt,
    const float* __restrict__ bias, float* __restrict__ Cv)
{
    const int id = blockIdx.x;
    gemm_core(A, Bt, bias, Cv, 256, id >> 2, id & 3);
}

// ---------------- sampler: batched gathers, schedule pinned -------------------
__global__ __launch_bounds__(256, 4) void sample_f16(
    const _Float16* __restrict__ valh,   // [M,256] f16
    const float* __restrict__ refp,      // [B,Lq,4,2]
    const _Float16* __restrict__ offh,   // [M,384] f16: 0-255 offsets, 256-383 logits
    const float* __restrict__ W_out,     // [256,256] f32 (k-major)
    _Float16* __restrict__ wto,          // [256,256] f16 (n-major, k-contig)
    _Float16* __restrict__ acc_out)      // [M,256] f16
{
    // fold W_out transpose into the first 256 blocks (consumed next dispatch)
    if (blockIdx.x < 256)
        wto[blockIdx.x * 256 + threadIdx.x] =
            (_Float16)W_out[threadIdx.x * 256 + blockIdx.x];

    const int wave = threadIdx.x >> 6, lane = threadIdx.x & 63;
    const int q2 = lane >> 5, sl = lane & 31;
    const int bq = blockIdx.x * 8 + wave * 2 + q2;    // 0..21759
    const int b = bq / 5440;
    const int h = sl >> 2;          // head
    const int d8 = (sl & 3) * 8;    // channel octet within head

    const _Float16* off_row = offh + (size_t)bq * 384 + h * 32;
    const _Float16* att_row = offh + (size_t)bq * 384 + 256 + h * 16;
    const float* rp = refp + (size_t)bq * 8;

    const half8 ofr0 = *(const half8*)(off_row);
    const half8 ofr1 = *(const half8*)(off_row + 8);
    const half8 ofr2 = *(const half8*)(off_row + 16);
    const half8 ofr3 = *(const half8*)(off_row + 24);
    float lg[16];
    {
        const half8 t0 = *(const half8*)(att_row);
        const half8 t1 = *(const half8*)(att_row + 8);
#pragma unroll
        for (int j = 0; j < 8; ++j) { lg[j] = (float)t0[j]; lg[8 + j] = (float)t1[j]; }
    }
    float mx = -1e30f;
#pragma unroll
    for (int i = 0; i < 16; ++i) mx = fmaxf(mx, lg[i]);
    float s = 0.f;
#pragma unroll
    for (int i = 0; i < 16; ++i) { lg[i] = __expf(lg[i] - mx); s += lg[i]; }
    const float inv = 1.f / s;

    const float4 rp01 = *(const float4*)rp;
    const float4 rp23 = *(const float4*)(rp + 4);
    const float rxs[4] = {rp01.x, rp01.z, rp23.x, rp23.z};
    const float rys[4] = {rp01.y, rp01.w, rp23.y, rp23.w};

    const int Ws_[4] = {64, 32, 16, 8};
    const int starts_[4] = {0, 4096, 5120, 5376};

    half8 acc = splat8((_Float16)0.f);
#pragma unroll
    for (int l = 0; l < 4; ++l) {
        const int W = Ws_[l];
        const float fW = (float)W;
        const _Float16* vbase = valh + ((size_t)(b * 5440 + starts_[l])) * 256 + h * 32 + d8;
        const float rx = rxs[l], ry = rys[l];

        int idx_[16];
        _Float16 w_[16];
#pragma unroll
        for (int p = 0; p < 4; ++p) {
            const int pi = l * 4 + p;
            const float aw = lg[pi] * inv;
            float ox, oy;
            {
                const half8 src = (pi < 8) ? ((pi < 4) ? ofr0 : ofr1)
                                           : ((pi < 12) ? ofr2 : ofr3);
                const int e = (pi & 3) * 2;
                ox = (float)src[e];
                oy = (float)src[e + 1];
            }
            const float x = fmaf(rx, fW, ox) - 0.5f;
            const float y = fmaf(ry, fW, oy) - 0.5f;
            const float x0f = floorf(x), y0f = floorf(y);
            const int x0 = (int)x0f, y0 = (int)y0f;
            const float wx = x - x0f, wy = y - y0f;
            const bool okx0 = ((unsigned)x0 < (unsigned)W);
            const bool okx1 = ((unsigned)(x0 + 1) < (unsigned)W);
            const bool oky0 = ((unsigned)y0 < (unsigned)W);
            const bool oky1 = ((unsigned)(y0 + 1) < (unsigned)W);
            const int xc0 = min(max(x0, 0), W - 1);
            const int xc1 = min(max(x0 + 1, 0), W - 1);
            const int yc0 = min(max(y0, 0), W - 1);
            const int yc1 = min(max(y0 + 1, 0), W - 1);
            w_[p * 4 + 0] = (_Float16)((okx0 & oky0) ? (1.f - wx) * (1.f - wy) * aw : 0.f);
            w_[p * 4 + 1] = (_Float16)((okx1 & oky0) ? wx * (1.f - wy) * aw : 0.f);
            w_[p * 4 + 2] = (_Float16)((okx0 & oky1) ? (1.f - wx) * wy * aw : 0.f);
            w_[p * 4 + 3] = (_Float16)((okx1 & oky1) ? wx * wy * aw : 0.f);
            idx_[p * 4 + 0] = (yc0 * W + xc0) * 256;
            idx_[p * 4 + 1] = (yc0 * W + xc1) * 256;
            idx_[p * 4 + 2] = (yc1 * W + xc0) * 256;
            idx_[p * 4 + 3] = (yc1 * W + xc1) * 256;
        }

        // pin: all 16 loads issue before any consumer (progressive vmcnt drain)
        __builtin_amdgcn_sched_barrier(0);
        half8 c_[16];
#pragma unroll
        for (int i = 0; i < 16; ++i)
            c_[i] = *(const half8*)(vbase + idx_[i]);
        __builtin_amdgcn_sched_barrier(0);
#pragma unroll
        for (int i = 0; i < 16; ++i)
            acc += c_[i] * splat8(w_[i]);
    }

    *(half8*)(acc_out + (size_t)bq * 256 + h * 32 + d8) = acc;
}

extern "C" void kernel_launch(void* const* d_in, const int* in_sizes, int n_in,
                              void* d_out, int out_size, void* d_ws, size_t ws_size,
                              hipStream_t stream) {
    const float* query  = (const float*)d_in[0];
    const float* refp   = (const float*)d_in[1];
    const float* value  = (const float*)d_in[2];
    const float* W_off  = (const float*)d_in[3];
    const float* b_off  = (const float*)d_in[4];
    const float* W_attn = (const float*)d_in[5];
    const float* b_attn = (const float*)d_in[6];
    const float* W_val  = (const float*)d_in[7];
    const float* b_val  = (const float*)d_in[8];
    const float* W_out  = (const float*)d_in[9];
    const float* b_out  = (const float*)d_in[10];
    float* out = (float*)d_out;

    const size_t M = M_TOTAL;

    _Float16* valh  = (_Float16*)d_ws;                // M*256
    _Float16* offh  = valh + M * 256;                 // M*384
    _Float16* acc16 = offh + M * 384;                 // M*256
    _Float16* wto   = acc16 + M * 256;                // 256*256

    dim3 blk(256);
    gemm12_cvt<<<dim3(850), blk, 0, stream>>>(
        value, query, W_val, W_off, W_attn, b_val, b_off, b_attn, valh, offh);
    sample_f16<<<dim3(M / 8), blk, 0, stream>>>(valh, refp, offh, W_out, wto, acc16);
    gemm_single<<<dim3(680), blk, 0, stream>>>(acc16, wto, b_out, out);
}